// Round 4
// baseline (3625.209 us; speedup 1.0000x reference)
//
#include <hip/hip_runtime.h>

#define NSTEPS 64

// Packed weight layout in d_ws (float element offsets). All 16B-aligned.
// w1[3][32] | b1[32] | w2[32][32] | b2[32] | w3t[3][32] | b3[3]+pad
#define PW_W1   0
#define PW_B1   96
#define PW_W2   128
#define PW_B2   1152
#define PW_W3T  1184
#define PW_B3   1280
#define PW_TOTAL 1284

__global__ void pack_weights(const float* __restrict__ w1, const float* __restrict__ b1,
                             const float* __restrict__ w2, const float* __restrict__ b2,
                             const float* __restrict__ w3, const float* __restrict__ b3,
                             float* __restrict__ wt)
{
    const int t = threadIdx.x;
    for (int i = t; i < 96; i += 256)   wt[PW_W1 + i] = w1[i];
    for (int i = t; i < 32; i += 256)   wt[PW_B1 + i] = b1[i];
    for (int i = t; i < 1024; i += 256) wt[PW_W2 + i] = w2[i];
    for (int i = t; i < 32; i += 256)   wt[PW_B2 + i] = b2[i];
    // w3 transposed: w3t[d][j] = w3[j][d]
    for (int i = t; i < 96; i += 256)   wt[PW_W3T + (i % 3) * 32 + (i / 3)] = w3[i];
    if (t < 3) wt[PW_B3 + t] = b3[t];
    if (t == 3) wt[PW_B3 + 3] = 0.0f;
}

__global__ __launch_bounds__(256, 2)
void ode_rk4_kernel(const float* __restrict__ x,
                    const float* __restrict__ samples,
                    const float* __restrict__ wt,
                    const float* __restrict__ w_out, const float* __restrict__ b_out,
                    float* __restrict__ out, int B)
{
    const int r = blockIdx.x * blockDim.x + threadIdx.x;
    if (r >= B) return;

    const float4* W = (const float4*)wt;   // uniform base -> SGPR + imm offsets

    const float maxT = samples[7];
    const float dt   = maxT / 64.0f;
    const float dt2  = 0.5f * dt;
    const float dt6  = dt / 6.0f;

    int sidx[8];
#pragma unroll
    for (int j = 0; j < 8; ++j) {
        int id = (int)rintf(samples[j] / dt) - 1;   // jnp.round = round-half-even
        id = id < 0 ? 0 : (id > NSTEPS - 1 ? NSTEPS - 1 : id);
        sidx[j] = id;
    }

    const float wo0 = w_out[0], wo1 = w_out[1], wo2 = w_out[2];
    const float bo  = b_out[0];

    float y0 = x[(size_t)r * 3 + 0];
    float y1 = x[(size_t)r * 3 + 1];
    float y2 = x[(size_t)r * 3 + 2];

#pragma unroll 1
    for (int s = 0; s < NSTEPS; ++s) {
        float acc0 = 0.f, acc1 = 0.f, acc2 = 0.f;
        float a0 = y0, a1 = y1, a2 = y2;

        // RK4 stage loop rolled: hot body is ONE eval (~13 KB, fits I$)
#pragma unroll 1
        for (int st = 0; st < 4; ++st) {
            // ---- layer 1: h1 = relu(a @ W1 + b1) ----
            float h1[32];
#pragma unroll
            for (int q = 0; q < 8; ++q) {
                float4 wa = W[PW_W1 / 4 + q];
                float4 wb = W[PW_W1 / 4 + 8 + q];
                float4 wc = W[PW_W1 / 4 + 16 + q];
                float4 bb = W[PW_B1 / 4 + q];
                h1[4*q+0] = fmaxf(fmaf(a2, wc.x, fmaf(a1, wb.x, fmaf(a0, wa.x, bb.x))), 0.f);
                h1[4*q+1] = fmaxf(fmaf(a2, wc.y, fmaf(a1, wb.y, fmaf(a0, wa.y, bb.y))), 0.f);
                h1[4*q+2] = fmaxf(fmaf(a2, wc.z, fmaf(a1, wb.z, fmaf(a0, wa.z, bb.z))), 0.f);
                h1[4*q+3] = fmaxf(fmaf(a2, wc.w, fmaf(a1, wb.w, fmaf(a0, wa.w, bb.w))), 0.f);
            }

            // ---- layers 2+3 fused by 8-column blocks (live set stays tiny) ----
            float4 b3v = W[PW_B3 / 4];
            float k0 = b3v.x, k1 = b3v.y, k2 = b3v.z;
#pragma unroll
            for (int jb = 0; jb < 4; ++jb) {
                float4 b2a = W[PW_B2 / 4 + jb * 2];
                float4 b2b = W[PW_B2 / 4 + jb * 2 + 1];
                float h[8] = {b2a.x, b2a.y, b2a.z, b2a.w, b2b.x, b2b.y, b2b.z, b2b.w};
#pragma unroll
                for (int i = 0; i < 32; ++i) {
                    float4 w0 = W[PW_W2 / 4 + i * 8 + jb * 2];
                    float4 w4 = W[PW_W2 / 4 + i * 8 + jb * 2 + 1];
                    float v = h1[i];
                    h[0] = fmaf(v, w0.x, h[0]); h[1] = fmaf(v, w0.y, h[1]);
                    h[2] = fmaf(v, w0.z, h[2]); h[3] = fmaf(v, w0.w, h[3]);
                    h[4] = fmaf(v, w4.x, h[4]); h[5] = fmaf(v, w4.y, h[5]);
                    h[6] = fmaf(v, w4.z, h[6]); h[7] = fmaf(v, w4.w, h[7]);
                }
#pragma unroll
                for (int e = 0; e < 8; ++e) h[e] = fmaxf(h[e], 0.f);
#pragma unroll
                for (int d = 0; d < 3; ++d) {
                    float4 t0 = W[PW_W3T / 4 + d * 8 + jb * 2];
                    float4 t4 = W[PW_W3T / 4 + d * 8 + jb * 2 + 1];
                    float sv = fmaf(h[0], t0.x, fmaf(h[1], t0.y, fmaf(h[2], t0.z, h[3] * t0.w)));
                    sv = fmaf(h[4], t4.x, fmaf(h[5], t4.y, fmaf(h[6], t4.z, fmaf(h[7], t4.w, sv))));
                    if (d == 0) k0 += sv; else if (d == 1) k1 += sv; else k2 += sv;
                }
            }

            const float ca = (st == 1 || st == 2) ? 2.0f : 1.0f;
            acc0 = fmaf(ca, k0, acc0); acc1 = fmaf(ca, k1, acc1); acc2 = fmaf(ca, k2, acc2);
            const float ci = (st == 2) ? dt : dt2;
            a0 = fmaf(ci, k0, y0); a1 = fmaf(ci, k1, y1); a2 = fmaf(ci, k2, y2);
        }
        y0 = fmaf(dt6, acc0, y0); y1 = fmaf(dt6, acc1, y1); y2 = fmaf(dt6, acc2, y2);

#pragma unroll
        for (int j = 0; j < 8; ++j) {
            if (sidx[j] == s) {
                out[(size_t)j * B + r] = fmaf(y2, wo2, fmaf(y1, wo1, fmaf(y0, wo0, bo)));
            }
        }
    }
}

extern "C" void kernel_launch(void* const* d_in, const int* in_sizes, int n_in,
                              void* d_out, int out_size, void* d_ws, size_t ws_size,
                              hipStream_t stream) {
    const float* x       = (const float*)d_in[0];
    const float* samples = (const float*)d_in[1];
    const float* w1      = (const float*)d_in[2];
    const float* b1      = (const float*)d_in[3];
    const float* w2      = (const float*)d_in[4];
    const float* b2      = (const float*)d_in[5];
    const float* w3      = (const float*)d_in[6];
    const float* b3      = (const float*)d_in[7];
    const float* w_out   = (const float*)d_in[8];
    const float* b_out   = (const float*)d_in[9];
    float* out = (float*)d_out;
    float* wt  = (float*)d_ws;   // PW_TOTAL floats of packed weights

    const int B = in_sizes[0] / 3;

    pack_weights<<<1, 256, 0, stream>>>(w1, b1, w2, b2, w3, b3, wt);

    const int block = 256;
    const int grid = (B + block - 1) / block;
    ode_rk4_kernel<<<grid, block, 0, stream>>>(
        x, samples, wt, w_out, b_out, out, B);
}

// Round 5
// 436.718 us; speedup vs baseline: 8.3010x; 8.3010x over previous
//
#include <hip/hip_runtime.h>

#define NSTEPS 64

typedef __attribute__((ext_vector_type(8))) short short8;   // 8 bf16 (4 VGPRs)
typedef __attribute__((ext_vector_type(4))) float float4_;  // 4 fp32 (MFMA C/D)

// fp32 -> bf16, round-to-nearest-even
__device__ __forceinline__ short f2bf(float f) {
    union { float f; unsigned u; } v; v.f = f;
    unsigned r = v.u + 0x7fffu + ((v.u >> 16) & 1u);
    return (short)(r >> 16);
}

// MFMA 16x16x32 bf16 layouts (guide §3, HW-verified m89/m91/m120):
//   A[m][k]:  m = lane&15, k = (lane>>4)*8 + j   (j = frag element 0..7)
//   B[k][n]:  n = lane&15, k = (lane>>4)*8 + j
//   C/D[r][c]: c = lane&15, r = (lane>>4)*4 + reg
__global__ __launch_bounds__(256, 4)
void ode_rk4_mfma(const float* __restrict__ x,
                  const float* __restrict__ samples,
                  const float* __restrict__ w1, const float* __restrict__ b1,
                  const float* __restrict__ w2, const float* __restrict__ b2,
                  const float* __restrict__ w3, const float* __restrict__ b3,
                  const float* __restrict__ w_out, const float* __restrict__ b_out,
                  float* __restrict__ out, int B)
{
    const int lane  = threadIdx.x & 63;
    const int w     = threadIdx.x >> 6;       // wave in block (0..3)
    const int col16 = lane & 15;
    const int quad  = lane >> 4;              // 0..3

    // per-wave private LDS scratch (wave-synchronous, no __syncthreads)
    __shared__ __align__(16) float hbuf[4][16 * 36];  // h2 transpose, stride 36 (2-way banks = free)
    __shared__ __align__(16) float kbuf[4][16 * 4];   // k transpose [row][4]
    float* hb = hbuf[w];
    float* kb = kbuf[w];

    const int rowBase = (blockIdx.x * 4 + w) * 16;
    if (rowBase >= B) return;
    const int row = rowBase + col16;          // this lane's row (replicated over quads)

    // ---- persistent weight fragments (built once; reused 1024x) ----
    // layer1 slice for this lane: j = quad*8 + jl
    float w1a[8], w1b[8], w1c[8], b1l[8];
#pragma unroll
    for (int jl = 0; jl < 8; ++jl) {
        int j = quad * 8 + jl;
        w1a[jl] = w1[0 * 32 + j];
        w1b[jl] = w1[1 * 32 + j];
        w1c[jl] = w1[2 * 32 + j];
        b1l[jl] = b1[j];
    }
    // layer2 B-frags (two N-tiles) + bias C-frags
    short8 B2f0, B2f1;
#pragma unroll
    for (int jl = 0; jl < 8; ++jl) {
        int k = quad * 8 + jl;
        B2f0[jl] = f2bf(w2[k * 32 + col16]);
        B2f1[jl] = f2bf(w2[k * 32 + col16 + 16]);
    }
    float4_ Cb20, Cb21;
    {
        float v0 = b2[col16], v1 = b2[col16 + 16];
        Cb20 = (float4_){v0, v0, v0, v0};
        Cb21 = (float4_){v1, v1, v1, v1};
    }
    // layer3 B-frag (cols 0..2 valid) + bias C-frag
    short8 B3f;
#pragma unroll
    for (int jl = 0; jl < 8; ++jl) {
        int k = quad * 8 + jl;
        B3f[jl] = (col16 < 3) ? f2bf(w3[k * 3 + col16]) : (short)0;
    }
    float4_ Cb3;
    {
        float v = (col16 < 3) ? b3[col16] : 0.0f;
        Cb3 = (float4_){v, v, v, v};
    }

    // ---- scalars ----
    const float maxT = samples[7];
    const float dt   = maxT / 64.0f;
    const float dt2  = 0.5f * dt;
    const float dt6  = dt / 6.0f;

    int sidx[8];
#pragma unroll
    for (int j = 0; j < 8; ++j) {
        int id = (int)rintf(samples[j] / dt) - 1;   // jnp.round = RNE
        id = id < 0 ? 0 : (id > NSTEPS - 1 ? NSTEPS - 1 : id);
        sidx[j] = id;
    }
    const float wo0 = w_out[0], wo1 = w_out[1], wo2 = w_out[2];
    const float bo  = b_out[0];

    // state: row-per-lane (lane's row = rowBase+col16), replicated across quads
    float y0 = x[(size_t)row * 3 + 0];
    float y1 = x[(size_t)row * 3 + 1];
    float y2 = x[(size_t)row * 3 + 2];

#pragma unroll 1
    for (int s = 0; s < NSTEPS; ++s) {
        float acc0 = 0.f, acc1 = 0.f, acc2 = 0.f;
        float a0 = y0, a1 = y1, a2 = y2;

#pragma unroll 1
        for (int st = 0; st < 4; ++st) {
            // ---- layer1 on VALU, producing the layer2 A-frag directly ----
            // lane (m=col16, slice=quad) computes h1[m][quad*8+jl] = A2 element jl
            short8 A2;
#pragma unroll
            for (int jl = 0; jl < 8; ++jl) {
                float h = fmaf(a2, w1c[jl], fmaf(a1, w1b[jl], fmaf(a0, w1a[jl], b1l[jl])));
                A2[jl] = f2bf(fmaxf(h, 0.f));
            }

            // ---- layer2: two MFMAs, bias via C operand ----
            float4_ D20 = __builtin_amdgcn_mfma_f32_16x16x32_bf16(A2, B2f0, Cb20, 0, 0, 0);
            float4_ D21 = __builtin_amdgcn_mfma_f32_16x16x32_bf16(A2, B2f1, Cb21, 0, 0, 0);

            // ---- h2: C-layout -> LDS (raw fp32), then read back in A-layout ----
#pragma unroll
            for (int r = 0; r < 4; ++r) {
                hb[(quad * 4 + r) * 36 + col16]      = D20[r];
                hb[(quad * 4 + r) * 36 + col16 + 16] = D21[r];
            }
            const float* hr = hb + col16 * 36 + quad * 8;   // 8 contiguous fp32, 16B-aligned
            short8 A3;
#pragma unroll
            for (int jl = 0; jl < 8; ++jl)
                A3[jl] = f2bf(fmaxf(hr[jl], 0.f));          // relu + cvt on read side

            // ---- layer3: one MFMA (cols 0..2 meaningful) ----
            float4_ D3 = __builtin_amdgcn_mfma_f32_16x16x32_bf16(A3, B3f, Cb3, 0, 0, 0);

            // ---- k: C-layout -> row-per-lane via LDS ----
            if (col16 < 3) {
#pragma unroll
                for (int r = 0; r < 4; ++r)
                    kb[(quad * 4 + r) * 4 + col16] = D3[r];
            }
            const float* kr = kb + col16 * 4;   // lane's row; broadcast across quads
            float k0 = kr[0], k1 = kr[1], k2 = kr[2];

            const float ca = (st == 1 || st == 2) ? 2.0f : 1.0f;
            acc0 = fmaf(ca, k0, acc0); acc1 = fmaf(ca, k1, acc1); acc2 = fmaf(ca, k2, acc2);
            const float ci = (st == 2) ? dt : dt2;
            a0 = fmaf(ci, k0, y0); a1 = fmaf(ci, k1, y1); a2 = fmaf(ci, k2, y2);
        }
        y0 = fmaf(dt6, acc0, y0); y1 = fmaf(dt6, acc1, y1); y2 = fmaf(dt6, acc2, y2);

        if (quad == 0) {
#pragma unroll
            for (int j = 0; j < 8; ++j) {
                if (sidx[j] == s) {
                    out[(size_t)j * B + row] = fmaf(y2, wo2, fmaf(y1, wo1, fmaf(y0, wo0, bo)));
                }
            }
        }
    }
}

extern "C" void kernel_launch(void* const* d_in, const int* in_sizes, int n_in,
                              void* d_out, int out_size, void* d_ws, size_t ws_size,
                              hipStream_t stream) {
    const float* x       = (const float*)d_in[0];
    const float* samples = (const float*)d_in[1];
    const float* w1      = (const float*)d_in[2];
    const float* b1      = (const float*)d_in[3];
    const float* w2      = (const float*)d_in[4];
    const float* b2      = (const float*)d_in[5];
    const float* w3      = (const float*)d_in[6];
    const float* b3      = (const float*)d_in[7];
    const float* w_out   = (const float*)d_in[8];
    const float* b_out   = (const float*)d_in[9];
    float* out = (float*)d_out;

    const int B = in_sizes[0] / 3;           // 131072
    const int rowsPerBlock = 64;             // 4 waves x 16 rows
    const int grid = (B + rowsPerBlock - 1) / rowsPerBlock;
    ode_rk4_mfma<<<grid, 256, 0, stream>>>(
        x, samples, w1, b1, w2, b2, w3, b3, w_out, b_out, out, B);
}

// Round 6
// 394.161 us; speedup vs baseline: 9.1973x; 1.1080x over previous
//
#include <hip/hip_runtime.h>

#define NSTEPS 64

typedef __attribute__((ext_vector_type(8))) short short8;   // 8 bf16 (4 VGPRs)
typedef __attribute__((ext_vector_type(4))) float float4_;  // 4 fp32 (MFMA C/D)

// pack two fp32 -> bf16x2 (round-half-up: +0x8000 then take hi16; 3 VALU ops)
__device__ __forceinline__ int pack2_bf16(float a, float b) {
    union { float f; unsigned u; } ua, ub; ua.f = a; ub.f = b;
    unsigned ra = ua.u + 0x8000u;
    unsigned rb = ub.u + 0x8000u;
    // result = (hi16(rb) << 16) | hi16(ra)
    return (int)__builtin_amdgcn_perm(rb, ra, 0x07060302);
}

// MFMA 16x16x32 bf16 layouts (HW-verified R4: passed with this orientation):
//   A[m][k]:  m = lane&15, k = (lane>>4)*8 + j
//   B[k][n]:  n = lane&15, k = (lane>>4)*8 + j   (same register mapping as A!)
//   C/D:      D[m = (lane>>4)*4 + reg][n = lane&15]
// Transposed trick: D2 = mfma(A=W2^T frag, B=h1 frag) => lane holds h2^T
// rows j2 = quad*4+reg for its own sample row n = lane&15. Layer 3 then runs
// per-lane on fp32 VALU + a 4-quad shfl_xor reduction. No LDS arrays at all.
__global__ __launch_bounds__(256, 4)
void ode_rk4_mfma(const float* __restrict__ x,
                  const float* __restrict__ samples,
                  const float* __restrict__ w1, const float* __restrict__ b1,
                  const float* __restrict__ w2, const float* __restrict__ b2,
                  const float* __restrict__ w3, const float* __restrict__ b3,
                  const float* __restrict__ w_out, const float* __restrict__ b_out,
                  float* __restrict__ out, int B)
{
    const int lane  = threadIdx.x & 63;
    const int w     = threadIdx.x >> 6;       // wave in block (0..3)
    const int col16 = lane & 15;              // this lane's sample row (mod 16)
    const int quad  = lane >> 4;              // 0..3

    const int rowBase = (blockIdx.x * 4 + w) * 16;
    const int row = rowBase + col16;          // lane's row (replicated over quads)

    // ---- persistent operands (built once; reused 1024 evals) ----
    // layer1 weights, j = quad*8 + jl  (produces h1 directly in A/B frag layout)
    float w1a[8], w1b[8], w1c[8], b1l[8];
#pragma unroll
    for (int jl = 0; jl < 8; ++jl) {
        int j = quad * 8 + jl;
        w1a[jl] = w1[0 * 32 + j];
        w1b[jl] = w1[1 * 32 + j];
        w1c[jl] = w1[2 * 32 + j];
        b1l[jl] = b1[j];
    }
    // W2^T A-frags: A[m=j2][k=i1] = w2[i1*32 + j2]; two j2 tiles (0..15, 16..31)
    short8 W2Ta, W2Tb;
#pragma unroll
    for (int jl = 0; jl < 8; ++jl) {
        int i1 = quad * 8 + jl;
        W2Ta[jl] = (short)(pack2_bf16(w2[i1 * 32 + col16], 0.f) & 0xffff);
        W2Tb[jl] = (short)(pack2_bf16(w2[i1 * 32 + col16 + 16], 0.f) & 0xffff);
    }
    // bias C-frags: Cb2a[reg] = b2[j2 = quad*4+reg]  (broadcast over rows)
    float4_ Cb2a, Cb2b;
#pragma unroll
    for (int r = 0; r < 4; ++r) {
        Cb2a[r] = b2[quad * 4 + r];
        Cb2b[r] = b2[16 + quad * 4 + r];
    }
    // layer3 weights resident per lane (fp32): j2 = quad*4+r and 16+quad*4+r
    float w3A0[4], w3A1[4], w3A2[4], w3B0[4], w3B1[4], w3B2[4];
#pragma unroll
    for (int r = 0; r < 4; ++r) {
        int jA = quad * 4 + r, jB = 16 + quad * 4 + r;
        w3A0[r] = w3[jA * 3 + 0]; w3A1[r] = w3[jA * 3 + 1]; w3A2[r] = w3[jA * 3 + 2];
        w3B0[r] = w3[jB * 3 + 0]; w3B1[r] = w3[jB * 3 + 1]; w3B2[r] = w3[jB * 3 + 2];
    }

    // ---- scalars ----
    const float maxT = samples[7];
    const float dt   = maxT / 64.0f;
    const float dt2  = 0.5f * dt;
    const float dt6  = dt / 6.0f;

    int sidx[8];
#pragma unroll
    for (int j = 0; j < 8; ++j) {
        int id = (int)rintf(samples[j] / dt) - 1;   // jnp.round = RNE
        id = id < 0 ? 0 : (id > NSTEPS - 1 ? NSTEPS - 1 : id);
        sidx[j] = id;
    }
    const float wo0 = w_out[0], wo1 = w_out[1], wo2 = w_out[2];
    const float bo  = b_out[0];

    float y0 = x[(size_t)row * 3 + 0];
    float y1 = x[(size_t)row * 3 + 1];
    float y2 = x[(size_t)row * 3 + 2];

#pragma unroll 1
    for (int s = 0; s < NSTEPS; ++s) {
        float acc0 = 0.f, acc1 = 0.f, acc2 = 0.f;
        float a0 = y0, a1 = y1, a2 = y2;

#pragma unroll 1
        for (int st = 0; st < 4; ++st) {
            // ---- layer1 on VALU, result already in MFMA B-frag layout ----
            float hf[8];
#pragma unroll
            for (int jl = 0; jl < 8; ++jl) {
                float h = fmaf(a2, w1c[jl], fmaf(a1, w1b[jl], fmaf(a0, w1a[jl], b1l[jl])));
                hf[jl] = fmaxf(h, 0.f);
            }
            union { short8 s8; int i4[4]; } A2u;
            A2u.i4[0] = pack2_bf16(hf[0], hf[1]);
            A2u.i4[1] = pack2_bf16(hf[2], hf[3]);
            A2u.i4[2] = pack2_bf16(hf[4], hf[5]);
            A2u.i4[3] = pack2_bf16(hf[6], hf[7]);

            // ---- layer2 transposed: h2^T lands row-local, no transpose needed ----
            float4_ D20 = __builtin_amdgcn_mfma_f32_16x16x32_bf16(W2Ta, A2u.s8, Cb2a, 0, 0, 0);
            float4_ D21 = __builtin_amdgcn_mfma_f32_16x16x32_bf16(W2Tb, A2u.s8, Cb2b, 0, 0, 0);

            // ---- layer3 on fp32 VALU: partial dot over this lane's 8 j2 rows ----
            float p0 = 0.f, p1 = 0.f, p2 = 0.f;
#pragma unroll
            for (int r = 0; r < 4; ++r) {
                float hA = fmaxf(D20[r], 0.f);
                float hB = fmaxf(D21[r], 0.f);
                p0 = fmaf(hB, w3B0[r], fmaf(hA, w3A0[r], p0));
                p1 = fmaf(hB, w3B1[r], fmaf(hA, w3A1[r], p1));
                p2 = fmaf(hB, w3B2[r], fmaf(hA, w3A2[r], p2));
            }
            // reduce across the 4 quads (lanes l, l^16, l^32, l^48 share a row)
            p0 += __shfl_xor(p0, 16); p1 += __shfl_xor(p1, 16); p2 += __shfl_xor(p2, 16);
            p0 += __shfl_xor(p0, 32); p1 += __shfl_xor(p1, 32); p2 += __shfl_xor(p2, 32);
            float k0 = p0 + b3[0], k1 = p1 + b3[1], k2 = p2 + b3[2];

            const float ca = (st == 1 || st == 2) ? 2.0f : 1.0f;
            acc0 = fmaf(ca, k0, acc0); acc1 = fmaf(ca, k1, acc1); acc2 = fmaf(ca, k2, acc2);
            const float ci = (st == 2) ? dt : dt2;
            a0 = fmaf(ci, k0, y0); a1 = fmaf(ci, k1, y1); a2 = fmaf(ci, k2, y2);
        }
        y0 = fmaf(dt6, acc0, y0); y1 = fmaf(dt6, acc1, y1); y2 = fmaf(dt6, acc2, y2);

        if (quad == 0) {
#pragma unroll
            for (int j = 0; j < 8; ++j) {
                if (sidx[j] == s) {
                    out[(size_t)j * B + row] = fmaf(y2, wo2, fmaf(y1, wo1, fmaf(y0, wo0, bo)));
                }
            }
        }
    }
}

extern "C" void kernel_launch(void* const* d_in, const int* in_sizes, int n_in,
                              void* d_out, int out_size, void* d_ws, size_t ws_size,
                              hipStream_t stream) {
    const float* x       = (const float*)d_in[0];
    const float* samples = (const float*)d_in[1];
    const float* w1      = (const float*)d_in[2];
    const float* b1      = (const float*)d_in[3];
    const float* w2      = (const float*)d_in[4];
    const float* b2      = (const float*)d_in[5];
    const float* w3      = (const float*)d_in[6];
    const float* b3      = (const float*)d_in[7];
    const float* w_out   = (const float*)d_in[8];
    const float* b_out   = (const float*)d_in[9];
    float* out = (float*)d_out;

    const int B = in_sizes[0] / 3;           // 131072
    const int rowsPerBlock = 64;             // 4 waves x 16 rows
    const int grid = (B + rowsPerBlock - 1) / rowsPerBlock;
    ode_rk4_mfma<<<grid, 256, 0, stream>>>(
        x, samples, w1, b1, w2, b2, w3, b3, w_out, b_out, out, B);
}